// Round 3
// baseline (1008.107 us; speedup 1.0000x reference)
//
#include <hip/hip_runtime.h>
#include <hip/hip_bf16.h>

#define NV 200000
#define CO 64

__device__ __forceinline__ float bfbits_lo(unsigned int u){ union{unsigned int i; float f;} x; x.i = u << 16; return x.f; }
__device__ __forceinline__ float bfbits_hi(unsigned int u){ union{unsigned int i; float f;} x; x.i = u & 0xffff0000u; return x.f; }

// One wave = 64 lanes = 64 output channels. Each wave processes groups of 8
// voxels (8 f32 accumulators per lane), grid-striding over all N voxels.
// Per offset k: W[k][c][lane] preloaded to registers (coalesced), gathered
// feature rows broadcast-loaded (all lanes same address -> 1 L1 transaction).
template<int CIN, bool IN_BF16, bool LRELU, bool BIAS, bool OUT_BF16>
__global__ __launch_bounds__(256) void conv_k(
    const void* __restrict__ xin,      // [N, CIN] f32 or bf16
    const int*  __restrict__ nbr,      // [9, N]
    const float* __restrict__ Wk,      // [9, CIN, 64]
    const float* __restrict__ bias,    // [9, 64] or null
    void* __restrict__ outp,           // [N, 64] bf16 or f32
    float* __restrict__ s_sum, float* __restrict__ s_sq)
{
    const int lane = threadIdx.x & 63;
    const int wid  = blockIdx.x * (blockDim.x >> 6) + (threadIdx.x >> 6);
    const int nwaves = gridDim.x * (blockDim.x >> 6);
    float ssum = 0.f, ssq = 0.f;

    for (int base = wid * 8; base < NV; base += nwaves * 8) {
        float acc[8] = {0.f,0.f,0.f,0.f,0.f,0.f,0.f,0.f};
        #pragma unroll 1
        for (int k = 0; k < 9; ++k) {
            float w[CIN];
            #pragma unroll
            for (int c = 0; c < CIN; ++c) w[c] = Wk[(k * CIN + c) * CO + lane];
            float bk = 0.f;
            if (BIAS) bk = bias[k * CO + lane];
            int myidx = -1;
            if (lane < 8 && base + lane < NV) myidx = nbr[k * NV + base + lane];
        #pragma unroll
        for (int v = 0; v < 8; ++v) {
                int iv = __shfl(myidx, v, 64);
                if (iv >= 0) {
                    if (IN_BF16) {
                        const uint4* xr = (const uint4*)((const unsigned short*)xin + (size_t)iv * CIN);
                        #pragma unroll
                        for (int c8 = 0; c8 < CIN / 8; ++c8) {
                            uint4 p = xr[c8];
                            acc[v] += bfbits_lo(p.x) * w[c8*8+0];
                            acc[v] += bfbits_hi(p.x) * w[c8*8+1];
                            acc[v] += bfbits_lo(p.y) * w[c8*8+2];
                            acc[v] += bfbits_hi(p.y) * w[c8*8+3];
                            acc[v] += bfbits_lo(p.z) * w[c8*8+4];
                            acc[v] += bfbits_hi(p.z) * w[c8*8+5];
                            acc[v] += bfbits_lo(p.w) * w[c8*8+6];
                            acc[v] += bfbits_hi(p.w) * w[c8*8+7];
                        }
                    } else {
                        const float4* xr = (const float4*)((const float*)xin + (size_t)iv * CIN);
                        #pragma unroll
                        for (int c4 = 0; c4 < CIN / 4; ++c4) {
                            float4 q = xr[c4];
                            acc[v] += q.x * w[c4*4+0];
                            acc[v] += q.y * w[c4*4+1];
                            acc[v] += q.z * w[c4*4+2];
                            acc[v] += q.w * w[c4*4+3];
                        }
                    }
                    if (BIAS) acc[v] += bk;   // once per VALID offset (masked-BN bias)
                }
            }
        }
        #pragma unroll
        for (int v = 0; v < 8; ++v) {
            int n = base + v;
            if (n < NV) {
                float val = acc[v];
                if (LRELU) val = (val > 0.f) ? val : 0.01f * val;
                ssum += val; ssq += val * val;
                if (OUT_BF16) ((__hip_bfloat16*)outp)[(size_t)n * CO + lane] = __float2bfloat16(val);
                else          ((float*)outp)[(size_t)n * CO + lane] = val;
            }
        }
    }
    atomicAdd(s_sum + lane, ssum);
    atomicAdd(s_sq  + lane, ssq);
}

// BN finalize: a = g*rsqrt(var+eps), c = b - mean*a. Two BNs per launch.
__global__ void bn_fin(const float* sum0, const float* sq0, const float* g0, const float* b0, float* a0, float* c0,
                       const float* sum1, const float* sq1, const float* g1, const float* b1, float* a1, float* c1)
{
    int j = threadIdx.x;
    const float inv_n = 1.f / (float)NV;
    if (blockIdx.x == 0) {
        float m = sum0[j] * inv_n;
        float v = sq0[j] * inv_n - m * m;
        float a = g0[j] * rsqrtf(v + 1e-5f);
        a0[j] = a; c0[j] = b0[j] - m * a;
    } else {
        float m = sum1[j] * inv_n;
        float v = sq1[j] * inv_n - m * m;
        float a = g1[j] * rsqrtf(v + 1e-5f);
        a1[j] = a; c1[j] = b1[j] - m * a;
    }
}

// Fold BN affine into next conv's weights: W'[k][c][j] = a[c]*W[k][c][j],
// bias[k][j] = sum_c c[c]*W[k][c][j]  (added once per valid offset).
__global__ void wtrans(const float* W0, const float* a0, const float* c0, float* Wo0, float* bias0,
                       const float* W1, const float* a1, const float* c1, float* Wo1, float* bias1)
{
    int k = blockIdx.x % 9;
    int s = blockIdx.x / 9;
    int j = threadIdx.x;
    const float* W = s ? W1 : W0;
    const float* a = s ? a1 : a0;
    const float* c = s ? c1 : c0;
    float* Wo = s ? Wo1 : Wo0;
    float* bias = s ? bias1 : bias0;
    float bs = 0.f;
    for (int ci = 0; ci < 64; ++ci) {
        float wv = W[(k * 64 + ci) * 64 + j];
        Wo[(k * 64 + ci) * 64 + j] = a[ci] * wv;
        bs += c[ci] * wv;
    }
    bias[k * 64 + j] = bs;
}

// out = a2*r2 + c2 + a02*sc2 + c02   (in-place on d_out; per-thread same index)
__global__ void final_k(float* __restrict__ out, const __hip_bfloat16* __restrict__ sc2,
                        const float* __restrict__ a2, const float* __restrict__ c2,
                        const float* __restrict__ a02, const float* __restrict__ c02)
{
    int i = blockIdx.x * blockDim.x + threadIdx.x;
    if (i >= NV * CO) return;
    int ch = i & 63;
    float r = out[i];
    float s = __bfloat162float(sc2[i]);
    out[i] = a2[ch] * r + c2[ch] + a02[ch] * s + c02[ch];
}

extern "C" void kernel_launch(void* const* d_in, const int* in_sizes, int n_in,
                              void* d_out, int out_size, void* d_ws, size_t ws_size,
                              hipStream_t stream)
{
    const float* feats = (const float*)d_in[0];
    const int*   nbr_a = (const int*)d_in[1];
    const int*   nbr_b = (const int*)d_in[2];
    const float* W1    = (const float*)d_in[3];
    const float* W1_2  = (const float*)d_in[4];
    const float* W2    = (const float*)d_in[5];
    const float* W3    = (const float*)d_in[6];
    const float* g0    = (const float*)d_in[7];
    const float* b0    = (const float*)d_in[8];
    const float* g0_2  = (const float*)d_in[9];
    const float* b0_2  = (const float*)d_in[10];
    const float* g1    = (const float*)d_in[11];
    const float* b1    = (const float*)d_in[12];
    const float* g2    = (const float*)d_in[13];
    const float* b2    = (const float*)d_in[14];

    char* ws = (char*)d_ws;
    size_t off = 0;
    auto alloc = [&](size_t bytes) { void* p = ws + off; off += (bytes + 255) & ~(size_t)255; return p; };
    __hip_bfloat16* sc1 = (__hip_bfloat16*)alloc((size_t)NV * CO * 2);
    __hip_bfloat16* r1  = (__hip_bfloat16*)alloc((size_t)NV * CO * 2);
    __hip_bfloat16* sc2 = (__hip_bfloat16*)alloc((size_t)NV * CO * 2);
    float* Wp_sc   = (float*)alloc(9 * 64 * 64 * 4);
    float* Wp_r    = (float*)alloc(9 * 64 * 64 * 4);
    float* bias_sc = (float*)alloc(9 * 64 * 4);
    float* bias_r  = (float*)alloc(9 * 64 * 4);
    float* stats   = (float*)alloc(8 * 64 * 4);
    float* sum1a = stats,       *sq1a = stats + 64;
    float* sum1b = stats + 128, *sq1b = stats + 192;
    float* sum2a = stats + 256, *sq2a = stats + 320;
    float* sum2b = stats + 384, *sq2b = stats + 448;
    float* bn = (float*)alloc(8 * 64 * 4);
    float* a0 = bn,        *c0 = bn + 64;
    float* a1 = bn + 128,  *c1 = bn + 192;
    float* a02 = bn + 256, *c02 = bn + 320;
    float* a2 = bn + 384,  *c2 = bn + 448;

    hipMemsetAsync(stats, 0, 8 * 64 * 4, stream);

    dim3 blk(256);
    int grid = 1024;

    // pass 1: conv1 on both branches (lrelu + stats)
    conv_k<32, false, true, false, true><<<grid, blk, 0, stream>>>(feats, nbr_a, W1, nullptr, sc1, sum1a, sq1a);
    conv_k<32, false, true, false, true><<<grid, blk, 0, stream>>>(feats, nbr_b, W2, nullptr, r1,  sum1b, sq1b);
    // BN1 finalize (both branches), fold into conv2 weights
    bn_fin<<<2, 64, 0, stream>>>(sum1a, sq1a, g0, b0, a0, c0, sum1b, sq1b, g1, b1, a1, c1);
    wtrans<<<18, 64, 0, stream>>>(W1_2, a0, c0, Wp_sc, bias_sc, W3, a1, c1, Wp_r, bias_r);
    // pass 2: conv2 on both branches (stats); r2 raw f32 -> d_out
    conv_k<64, true, false, true, true ><<<grid, blk, 0, stream>>>(sc1, nbr_b, Wp_sc, bias_sc, sc2,  sum2a, sq2a);
    conv_k<64, true, false, true, false><<<grid, blk, 0, stream>>>(r1,  nbr_a, Wp_r,  bias_r,  d_out, sum2b, sq2b);
    // BN2 finalize + final fused add (in-place on d_out)
    bn_fin<<<2, 64, 0, stream>>>(sum2a, sq2a, g0_2, b0_2, a02, c02, sum2b, sq2b, g2, b2, a2, c2);
    final_k<<<(NV * CO + 255) / 256, 256, 0, stream>>>((float*)d_out, sc2, a2, c2, a02, c02);
}

// Round 6
// 548.178 us; speedup vs baseline: 1.8390x; 1.8390x over previous
//
#include <hip/hip_runtime.h>
#include <hip/hip_bf16.h>

#define NV 200000
#define CO 64

typedef short short8 __attribute__((ext_vector_type(8)));
typedef float f32x4 __attribute__((ext_vector_type(4)));

static __device__ __forceinline__ short f2bf(float f) {
    __hip_bfloat16 h = __float2bfloat16(f);
    return __builtin_bit_cast(short, h);
}

// Implicit-GEMM submanifold sparse conv via MFMA 16x16x32 bf16.
// One wave owns 64 voxels = 4 M-tiles of 16. A-fragment gathered per-lane
// straight from global (lane l reads 16B of row (l&15) at k-chunk (l>>4)*8).
// B = weights prepacked in fragment layout [9][CIN/32][4][64][8].
// BN-fold bias (once per VALID offset) done exactly via one extra MFMA per
// tile: A = 0/1 validity matrix from per-lane masks, B = packed bias frags.
template<int CIN, bool IN_F32, bool LRELU, bool BIAS, bool OUT_BF16>
__global__ __launch_bounds__(256) void conv_mfma(
    const void* __restrict__ xin,               // [N][CIN] f32 or bf16
    const int*  __restrict__ nbr,               // [9][N]
    const unsigned short* __restrict__ bpack,   // [9][CIN/32][4][64][8] bf16
    const unsigned short* __restrict__ biasB,   // [4][64][8] bf16 (BIAS only)
    void* __restrict__ outp,                    // [N][64] bf16 or f32
    float* __restrict__ s_sum, float* __restrict__ s_sq)
{
    constexpr int CHN = CIN / 32;
    const int lane = threadIdx.x & 63;
    const int wv = blockIdx.x * (blockDim.x >> 6) + (threadIdx.x >> 6);
    const int gbase = wv * 64;                  // 64 voxels per wave; NV = 3125*64
    if (gbase >= NV) return;
    const int g = lane >> 4;
    const int r16 = lane & 15;

    f32x4 acc[4][4];
    #pragma unroll
    for (int t = 0; t < 4; ++t)
        #pragma unroll
        for (int nt = 0; nt < 4; ++nt)
            acc[t][nt] = (f32x4){0.f, 0.f, 0.f, 0.f};

    unsigned vmask[4] = {0u, 0u, 0u, 0u};

    #pragma unroll 1
    for (int k = 0; k < 9; ++k) {
        int iv[4];
        #pragma unroll
        for (int t = 0; t < 4; ++t) iv[t] = nbr[k * NV + gbase + t * 16 + r16];
        if (BIAS) {
            #pragma unroll
            for (int t = 0; t < 4; ++t) vmask[t] |= (iv[t] >= 0 ? 1u : 0u) << k;
        }
        short8 bf[CHN][4];
        #pragma unroll
        for (int ch = 0; ch < CHN; ++ch)
            #pragma unroll
            for (int nt = 0; nt < 4; ++nt)
                bf[ch][nt] = *reinterpret_cast<const short8*>(
                    bpack + ((((size_t)k * CHN + ch) * 4 + nt) * 64 + lane) * 8);
        #pragma unroll
        for (int t = 0; t < 4; ++t) {
            const int ivt = iv[t] < 0 ? 0 : iv[t];
            #pragma unroll
            for (int ch = 0; ch < CHN; ++ch) {
                short8 av;
                if (IN_F32) {
                    const float* ap = (const float*)xin + (size_t)ivt * CIN + ch * 32 + g * 8;
                    float4 f0 = ((const float4*)ap)[0];
                    float4 f1 = ((const float4*)ap)[1];
                    av[0] = f2bf(f0.x); av[1] = f2bf(f0.y); av[2] = f2bf(f0.z); av[3] = f2bf(f0.w);
                    av[4] = f2bf(f1.x); av[5] = f2bf(f1.y); av[6] = f2bf(f1.z); av[7] = f2bf(f1.w);
                } else {
                    av = *reinterpret_cast<const short8*>(
                        (const unsigned short*)xin + (size_t)ivt * CIN + ch * 32 + g * 8);
                }
                if (iv[t] < 0) { short8 z = {0,0,0,0,0,0,0,0}; av = z; }
                #pragma unroll
                for (int nt = 0; nt < 4; ++nt)
                    acc[t][nt] = __builtin_amdgcn_mfma_f32_16x16x32_bf16(av, bf[ch][nt], acc[t][nt], 0, 0, 0);
            }
        }
    }

    if (BIAS) {
        short8 bb[4];
        #pragma unroll
        for (int nt = 0; nt < 4; ++nt)
            bb[nt] = *reinterpret_cast<const short8*>(biasB + ((size_t)nt * 64 + lane) * 8);
        #pragma unroll
        for (int t = 0; t < 4; ++t) {
            short8 vf;
            #pragma unroll
            for (int i = 0; i < 8; ++i) {
                int k9 = g * 8 + i;
                vf[i] = (k9 < 9 && ((vmask[t] >> k9) & 1u)) ? (short)0x3F80 : (short)0;
            }
            #pragma unroll
            for (int nt = 0; nt < 4; ++nt)
                acc[t][nt] = __builtin_amdgcn_mfma_f32_16x16x32_bf16(vf, bb[nt], acc[t][nt], 0, 0, 0);
        }
    }

    float ss[4] = {0,0,0,0}, sq[4] = {0,0,0,0};
    #pragma unroll
    for (int t = 0; t < 4; ++t)
        #pragma unroll
        for (int nt = 0; nt < 4; ++nt)
            #pragma unroll
            for (int rr = 0; rr < 4; ++rr) {
                float val = acc[t][nt][rr];
                if (LRELU) val = val > 0.f ? val : 0.01f * val;
                ss[nt] += val; sq[nt] += val * val;
                const size_t o = (size_t)(gbase + t * 16 + g * 4 + rr) * CO + nt * 16 + r16;
                if (OUT_BF16) ((__hip_bfloat16*)outp)[o] = __float2bfloat16(val);
                else          ((float*)outp)[o] = val;
            }
    #pragma unroll
    for (int nt = 0; nt < 4; ++nt) {
        float a = ss[nt], b = sq[nt];
        a += __shfl_xor(a, 16); a += __shfl_xor(a, 32);
        b += __shfl_xor(b, 16); b += __shfl_xor(b, 32);
        if (lane < 16) {
            atomicAdd(s_sum + nt * 16 + lane, a);
            atomicAdd(s_sq  + nt * 16 + lane, b);
        }
    }
}

// Pack conv1 weights (f32 [9][32][64]) into B-fragment layout bf16.
__global__ void prepack_w32(const float* __restrict__ W1, const float* __restrict__ W2,
                            unsigned short* __restrict__ P1, unsigned short* __restrict__ P2)
{
    int s = blockIdx.x / 9, k = blockIdx.x % 9, l = threadIdx.x;
    const float* W = s ? W2 : W1;
    unsigned short* P = s ? P2 : P1;
    int g = l >> 4, r16 = l & 15;
    for (int nt = 0; nt < 4; ++nt)
        for (int i = 0; i < 8; ++i) {
            int c = g * 8 + i, j = nt * 16 + r16;
            P[(((size_t)k * 4 + nt) * 64 + l) * 8 + i] =
                (unsigned short)f2bf(W[((size_t)k * 32 + c) * 64 + j]);
        }
}

// BN finalize: a = g*rsqrt(var+eps), c = b - mean*a. Two BNs per launch.
__global__ void bn_fin(const float* sum0, const float* sq0, const float* g0, const float* b0, float* a0, float* c0,
                       const float* sum1, const float* sq1, const float* g1, const float* b1, float* a1, float* c1)
{
    int j = threadIdx.x;
    const float inv_n = 1.f / (float)NV;
    if (blockIdx.x == 0) {
        float m = sum0[j] * inv_n;
        float v = sq0[j] * inv_n - m * m;
        float a = g0[j] * rsqrtf(v + 1e-5f);
        a0[j] = a; c0[j] = b0[j] - m * a;
    } else {
        float m = sum1[j] * inv_n;
        float v = sq1[j] * inv_n - m * m;
        float a = g1[j] * rsqrtf(v + 1e-5f);
        a1[j] = a; c1[j] = b1[j] - m * a;
    }
}

// Fold BN affine into conv2 weights, emit packed bf16 B-fragments + f32 bias.
__global__ void wtrans(const float* W0, const float* a0v, const float* c0v, unsigned short* P0, float* bias0,
                       const float* W1, const float* a1v, const float* c1v, unsigned short* P1, float* bias1)
{
    int s = blockIdx.x / 9, k = blockIdx.x % 9, l = threadIdx.x;
    const float* W  = s ? W1 : W0;
    const float* av = s ? a1v : a0v;
    const float* cv = s ? c1v : c0v;
    unsigned short* P = s ? P1 : P0;
    float* bias = s ? bias1 : bias0;
    int g = l >> 4, r16 = l & 15;
    for (int ch = 0; ch < 2; ++ch)
        for (int nt = 0; nt < 4; ++nt)
            for (int i = 0; i < 8; ++i) {
                int c = ch * 32 + g * 8 + i, j = nt * 16 + r16;
                P[((((size_t)k * 2 + ch) * 4 + nt) * 64 + l) * 8 + i] =
                    (unsigned short)f2bf(av[c] * W[((size_t)k * 64 + c) * 64 + j]);
            }
    float bs = 0.f;
    for (int c = 0; c < 64; ++c) bs += cv[c] * W[((size_t)k * 64 + c) * 64 + l];
    bias[k * 64 + l] = bs;
}

// Pack bias [9][64] f32 into validity-MFMA B-fragment layout (K=32, 9 live rows).
__global__ void wpack_bias(const float* bias0, unsigned short* B0,
                           const float* bias1, unsigned short* B1)
{
    int s = blockIdx.x, l = threadIdx.x;
    const float* bias = s ? bias1 : bias0;
    unsigned short* B = s ? B1 : B0;
    int g = l >> 4, r16 = l & 15;
    for (int nt = 0; nt < 4; ++nt)
        for (int i = 0; i < 8; ++i) {
            int k9 = g * 8 + i;
            B[((size_t)nt * 64 + l) * 8 + i] =
                k9 < 9 ? (unsigned short)f2bf(bias[k9 * 64 + nt * 16 + r16]) : (unsigned short)0;
        }
}

// out = a2*r2 + c2 + a02*sc2 + c02   (in-place on d_out)
__global__ void final_k(float* __restrict__ out, const __hip_bfloat16* __restrict__ sc2,
                        const float* __restrict__ a2, const float* __restrict__ c2,
                        const float* __restrict__ a02, const float* __restrict__ c02)
{
    int i = blockIdx.x * blockDim.x + threadIdx.x;
    if (i >= NV * CO) return;
    int ch = i & 63;
    float r = out[i];
    float s = __bfloat162float(sc2[i]);
    out[i] = a2[ch] * r + c2[ch] + a02[ch] * s + c02[ch];
}

extern "C" void kernel_launch(void* const* d_in, const int* in_sizes, int n_in,
                              void* d_out, int out_size, void* d_ws, size_t ws_size,
                              hipStream_t stream)
{
    const float* feats = (const float*)d_in[0];
    const int*   nbr_a = (const int*)d_in[1];
    const int*   nbr_b = (const int*)d_in[2];
    const float* W1    = (const float*)d_in[3];
    const float* W1_2  = (const float*)d_in[4];
    const float* W2    = (const float*)d_in[5];
    const float* W3    = (const float*)d_in[6];
    const float* g0    = (const float*)d_in[7];
    const float* b0    = (const float*)d_in[8];
    const float* g0_2  = (const float*)d_in[9];
    const float* b0_2  = (const float*)d_in[10];
    const float* g1    = (const float*)d_in[11];
    const float* b1    = (const float*)d_in[12];
    const float* g2    = (const float*)d_in[13];
    const float* b2    = (const float*)d_in[14];

    char* ws = (char*)d_ws;
    size_t off = 0;
    auto alloc = [&](size_t bytes) { void* p = ws + off; off += (bytes + 255) & ~(size_t)255; return p; };
    __hip_bfloat16* sc1 = (__hip_bfloat16*)alloc((size_t)NV * CO * 2);
    __hip_bfloat16* r1  = (__hip_bfloat16*)alloc((size_t)NV * CO * 2);
    __hip_bfloat16* sc2 = (__hip_bfloat16*)alloc((size_t)NV * CO * 2);
    unsigned short* P1a = (unsigned short*)alloc((size_t)9 * 4 * 64 * 8 * 2);       // conv1 sc weights
    unsigned short* P1b = (unsigned short*)alloc((size_t)9 * 4 * 64 * 8 * 2);       // conv1 r weights
    unsigned short* P2a = (unsigned short*)alloc((size_t)9 * 2 * 4 * 64 * 8 * 2);   // conv2 sc folded
    unsigned short* P2b = (unsigned short*)alloc((size_t)9 * 2 * 4 * 64 * 8 * 2);   // conv2 r folded
    unsigned short* Bba = (unsigned short*)alloc((size_t)4 * 64 * 8 * 2);           // bias frags sc
    unsigned short* Bbb = (unsigned short*)alloc((size_t)4 * 64 * 8 * 2);           // bias frags r
    float* bias_sc = (float*)alloc(9 * 64 * 4);
    float* bias_r  = (float*)alloc(9 * 64 * 4);
    float* stats   = (float*)alloc(8 * 64 * 4);
    float* sum1a = stats,       *sq1a = stats + 64;
    float* sum1b = stats + 128, *sq1b = stats + 192;
    float* sum2a = stats + 256, *sq2a = stats + 320;
    float* sum2b = stats + 384, *sq2b = stats + 448;
    float* bn = (float*)alloc(8 * 64 * 4);
    float* a0 = bn,        *c0 = bn + 64;
    float* a1 = bn + 128,  *c1 = bn + 192;
    float* a02 = bn + 256, *c02 = bn + 320;
    float* a2 = bn + 384,  *c2 = bn + 448;

    hipMemsetAsync(stats, 0, 8 * 64 * 4, stream);

    const int NG = NV / 64;                 // 3125 wave-groups, exact
    const int cblocks = (NG + 3) / 4;       // 4 waves per 256-thread block

    prepack_w32<<<18, 64, 0, stream>>>(W1, W2, P1a, P1b);

    // pass 1: conv1 both branches (f32 input, lrelu, stats)
    conv_mfma<32, true, true, false, true><<<cblocks, 256, 0, stream>>>(feats, nbr_a, P1a, nullptr, sc1, sum1a, sq1a);
    conv_mfma<32, true, true, false, true><<<cblocks, 256, 0, stream>>>(feats, nbr_b, P1b, nullptr, r1,  sum1b, sq1b);
    // BN1 finalize, fold into conv2 weights (packed), pack bias frags
    bn_fin<<<2, 64, 0, stream>>>(sum1a, sq1a, g0, b0, a0, c0, sum1b, sq1b, g1, b1, a1, c1);
    wtrans<<<18, 64, 0, stream>>>(W1_2, a0, c0, P2a, bias_sc, W3, a1, c1, P2b, bias_r);
    wpack_bias<<<2, 64, 0, stream>>>(bias_sc, Bba, bias_r, Bbb);
    // pass 2: conv2 both branches (bf16 input, bias, stats); r2 raw f32 -> d_out
    conv_mfma<64, false, false, true, true ><<<cblocks, 256, 0, stream>>>(sc1, nbr_b, P2a, Bba, sc2,   sum2a, sq2a);
    conv_mfma<64, false, false, true, false><<<cblocks, 256, 0, stream>>>(r1,  nbr_a, P2b, Bbb, d_out, sum2b, sq2b);
    // BN2 finalize + final fused add
    bn_fin<<<2, 64, 0, stream>>>(sum2a, sq2a, g0_2, b0_2, a02, c02, sum2b, sq2b, g2, b2, a2, c2);
    final_k<<<(NV * CO + 255) / 256, 256, 0, stream>>>((float*)d_out, sc2, a2, c2, a02, c02);
}

// Round 9
// 313.703 us; speedup vs baseline: 3.2136x; 1.7474x over previous
//
#include <hip/hip_runtime.h>
#include <hip/hip_bf16.h>

#define NVOX 200000
#define CO 64

typedef short short8 __attribute__((ext_vector_type(8)));
typedef float f32x4 __attribute__((ext_vector_type(4)));

static __device__ __forceinline__ short f2bf(float f) {
    __hip_bfloat16 h = __float2bfloat16(f);
    return __builtin_bit_cast(short, h);
}

// Implicit-GEMM submanifold sparse conv via MFMA 16x16x32 bf16.
// One wave owns 32 voxels = 2 M-tiles of 16; 6250 waves per branch.
// Both branch convs of a pass run in ONE dispatch (gridDim.y selects branch)
// so they overlap (graph capture serializes separate launches).
// All 18 nbr indices preloaded upfront; k-loop unrolled x3 for load/MFMA overlap.
// BN-fold bias (once per VALID offset) via one extra MFMA per tile:
// A = 0/1 validity matrix, B = packed bias fragments.
template<int CIN, bool IN_F32, bool LRELU, bool BIAS, bool OUT0_BF16, bool OUT1_BF16>
__global__ __launch_bounds__(320) void conv_mfma2(
    const void* __restrict__ xin0, const void* __restrict__ xin1,
    const int*  __restrict__ nbr0, const int* __restrict__ nbr1,
    const unsigned short* __restrict__ pack0, const unsigned short* __restrict__ pack1,
    const unsigned short* __restrict__ biasB0, const unsigned short* __restrict__ biasB1,
    void* __restrict__ out0, void* __restrict__ out1,
    float* __restrict__ ssum0, float* __restrict__ ssq0,
    float* __restrict__ ssum1, float* __restrict__ ssq1)
{
    constexpr int CHN = CIN / 32;
    const int br = blockIdx.y;
    const void* xin              = br ? xin1 : xin0;
    const int* nbr               = br ? nbr1 : nbr0;
    const unsigned short* bpack  = br ? pack1 : pack0;
    const unsigned short* biasB  = br ? biasB1 : biasB0;
    void* outp                   = br ? out1 : out0;
    float* s_sum                 = br ? ssum1 : ssum0;
    float* s_sq                  = br ? ssq1 : ssq0;
    const bool OUT_BF16          = br ? OUT1_BF16 : OUT0_BF16;

    const int lane = threadIdx.x & 63;
    const int wblk = threadIdx.x >> 6;            // 0..4 (5 waves/block)
    const int wv   = blockIdx.x * 5 + wblk;       // 0..6249, exact
    const int gbase = wv * 32;                    // 32 voxels per wave
    const int g = lane >> 4, r16 = lane & 15;

    // Preload all neighbor indices (kills the addr-dependency stage of the chain).
    int iv[2][9];
    #pragma unroll
    for (int t = 0; t < 2; ++t)
        #pragma unroll
        for (int k = 0; k < 9; ++k)
            iv[t][k] = nbr[k * NVOX + gbase + t * 16 + r16];

    f32x4 acc[2][4];
    #pragma unroll
    for (int t = 0; t < 2; ++t)
        #pragma unroll
        for (int nt = 0; nt < 4; ++nt)
            acc[t][nt] = (f32x4){0.f, 0.f, 0.f, 0.f};

    #pragma unroll 3
    for (int k = 0; k < 9; ++k) {
        short8 bf[CHN][4];
        #pragma unroll
        for (int ch = 0; ch < CHN; ++ch)
            #pragma unroll
            for (int nt = 0; nt < 4; ++nt)
                bf[ch][nt] = *reinterpret_cast<const short8*>(
                    bpack + ((((size_t)k * CHN + ch) * 4 + nt) * 64 + lane) * 8);
        #pragma unroll
        for (int t = 0; t < 2; ++t) {
            const int ivk = iv[t][k];
            const int ivt = ivk < 0 ? 0 : ivk;
            #pragma unroll
            for (int ch = 0; ch < CHN; ++ch) {
                short8 av;
                if (IN_F32) {
                    const float* ap = (const float*)xin + (size_t)ivt * CIN + ch * 32 + g * 8;
                    float4 f0 = ((const float4*)ap)[0];
                    float4 f1 = ((const float4*)ap)[1];
                    av[0] = f2bf(f0.x); av[1] = f2bf(f0.y); av[2] = f2bf(f0.z); av[3] = f2bf(f0.w);
                    av[4] = f2bf(f1.x); av[5] = f2bf(f1.y); av[6] = f2bf(f1.z); av[7] = f2bf(f1.w);
                } else {
                    av = *reinterpret_cast<const short8*>(
                        (const unsigned short*)xin + (size_t)ivt * CIN + ch * 32 + g * 8);
                }
                if (ivk < 0) { short8 z = {0,0,0,0,0,0,0,0}; av = z; }
                #pragma unroll
                for (int nt = 0; nt < 4; ++nt)
                    acc[t][nt] = __builtin_amdgcn_mfma_f32_16x16x32_bf16(av, bf[ch][nt], acc[t][nt], 0, 0, 0);
            }
        }
    }

    if (BIAS) {
        short8 bb[4];
        #pragma unroll
        for (int nt = 0; nt < 4; ++nt)
            bb[nt] = *reinterpret_cast<const short8*>(biasB + ((size_t)nt * 64 + lane) * 8);
        #pragma unroll
        for (int t = 0; t < 2; ++t) {
            unsigned vmask = 0;
            #pragma unroll
            for (int k = 0; k < 9; ++k) vmask |= (iv[t][k] >= 0 ? 1u : 0u) << k;
            short8 vf;
            #pragma unroll
            for (int i = 0; i < 8; ++i) {
                int k9 = g * 8 + i;
                vf[i] = (k9 < 9 && ((vmask >> k9) & 1u)) ? (short)0x3F80 : (short)0;
            }
            #pragma unroll
            for (int nt = 0; nt < 4; ++nt)
                acc[t][nt] = __builtin_amdgcn_mfma_f32_16x16x32_bf16(vf, bb[nt], acc[t][nt], 0, 0, 0);
        }
    }

    // Epilogue: lrelu, store, per-channel stats.
    float ss[4] = {0,0,0,0}, sq[4] = {0,0,0,0};
    #pragma unroll
    for (int t = 0; t < 2; ++t)
        #pragma unroll
        for (int nt = 0; nt < 4; ++nt)
            #pragma unroll
            for (int rr = 0; rr < 4; ++rr) {
                float val = acc[t][nt][rr];
                if (LRELU) val = val > 0.f ? val : 0.01f * val;
                ss[nt] += val; sq[nt] += val * val;
                const size_t o = (size_t)(gbase + t * 16 + g * 4 + rr) * CO + nt * 16 + r16;
                if (OUT_BF16) ((__hip_bfloat16*)outp)[o] = __float2bfloat16(val);
                else          ((float*)outp)[o] = val;
            }

    // Wave reduce over the 4 lane-groups sharing r16, then block reduce in LDS,
    // then one atomic per channel per block.
    __shared__ float lsum[5][64];
    __shared__ float lsq[5][64];
    #pragma unroll
    for (int nt = 0; nt < 4; ++nt) {
        float a = ss[nt], b = sq[nt];
        a += __shfl_xor(a, 16); a += __shfl_xor(a, 32);
        b += __shfl_xor(b, 16); b += __shfl_xor(b, 32);
        if (lane < 16) { lsum[wblk][nt * 16 + r16] = a; lsq[wblk][nt * 16 + r16] = b; }
    }
    __syncthreads();
    if (threadIdx.x < 64) {
        float a = 0.f, b = 0.f;
        #pragma unroll
        for (int w = 0; w < 5; ++w) { a += lsum[w][threadIdx.x]; b += lsq[w][threadIdx.x]; }
        atomicAdd(s_sum + threadIdx.x, a);
        atomicAdd(s_sq  + threadIdx.x, b);
    }
}

// Pack conv1 weights (f32 [9][32][64]) into B-fragment layout bf16.
__global__ void prepack_w32(const float* __restrict__ W1, const float* __restrict__ W2,
                            unsigned short* __restrict__ P1, unsigned short* __restrict__ P2)
{
    int s = blockIdx.x / 9, k = blockIdx.x % 9, l = threadIdx.x;
    const float* W = s ? W2 : W1;
    unsigned short* P = s ? P2 : P1;
    int g = l >> 4, r16 = l & 15;
    for (int nt = 0; nt < 4; ++nt)
        for (int i = 0; i < 8; ++i) {
            int c = g * 8 + i, j = nt * 16 + r16;
            P[(((size_t)k * 4 + nt) * 64 + l) * 8 + i] =
                (unsigned short)f2bf(W[((size_t)k * 32 + c) * 64 + j]);
        }
}

// BN finalize: a = g*rsqrt(var+eps), c = b - mean*a. Two BNs per launch.
__global__ void bn_fin(const float* sum0, const float* sq0, const float* g0, const float* b0, float* a0, float* c0,
                       const float* sum1, const float* sq1, const float* g1, const float* b1, float* a1, float* c1)
{
    int j = threadIdx.x;
    const float inv_n = 1.f / (float)NVOX;
    if (blockIdx.x == 0) {
        float m = sum0[j] * inv_n;
        float v = sq0[j] * inv_n - m * m;
        float a = g0[j] * rsqrtf(v + 1e-5f);
        a0[j] = a; c0[j] = b0[j] - m * a;
    } else {
        float m = sum1[j] * inv_n;
        float v = sq1[j] * inv_n - m * m;
        float a = g1[j] * rsqrtf(v + 1e-5f);
        a1[j] = a; c1[j] = b1[j] - m * a;
    }
}

// Fold BN affine into conv2 weights, emit packed bf16 B-fragments + f32 bias.
__global__ void wtrans(const float* W0, const float* a0v, const float* c0v, unsigned short* P0, float* bias0,
                       const float* W1, const float* a1v, const float* c1v, unsigned short* P1, float* bias1)
{
    int s = blockIdx.x / 9, k = blockIdx.x % 9, l = threadIdx.x;
    const float* W  = s ? W1 : W0;
    const float* av = s ? a1v : a0v;
    const float* cv = s ? c1v : c0v;
    unsigned short* P = s ? P1 : P0;
    float* bias = s ? bias1 : bias0;
    int g = l >> 4, r16 = l & 15;
    for (int ch = 0; ch < 2; ++ch)
        for (int nt = 0; nt < 4; ++nt)
            for (int i = 0; i < 8; ++i) {
                int c = ch * 32 + g * 8 + i, j = nt * 16 + r16;
                P[((((size_t)k * 2 + ch) * 4 + nt) * 64 + l) * 8 + i] =
                    (unsigned short)f2bf(av[c] * W[((size_t)k * 64 + c) * 64 + j]);
            }
    float bs = 0.f;
    for (int c = 0; c < 64; ++c) bs += cv[c] * W[((size_t)k * 64 + c) * 64 + l];
    bias[k * 64 + l] = bs;
}

// Pack bias [9][64] f32 into validity-MFMA B-fragment layout (K=32, 9 live rows).
__global__ void wpack_bias(const float* bias0, unsigned short* B0,
                           const float* bias1, unsigned short* B1)
{
    int s = blockIdx.x, l = threadIdx.x;
    const float* bias = s ? bias1 : bias0;
    unsigned short* B = s ? B1 : B0;
    int g = l >> 4, r16 = l & 15;
    for (int nt = 0; nt < 4; ++nt)
        for (int i = 0; i < 8; ++i) {
            int k9 = g * 8 + i;
            B[((size_t)nt * 64 + l) * 8 + i] =
                k9 < 9 ? (unsigned short)f2bf(bias[k9 * 64 + nt * 16 + r16]) : (unsigned short)0;
        }
}

// out = a2*r2 + c2 + a02*sc2 + c02   (in-place on d_out)
__global__ void final_k(float* __restrict__ out, const __hip_bfloat16* __restrict__ sc2,
                        const float* __restrict__ a2, const float* __restrict__ c2,
                        const float* __restrict__ a02, const float* __restrict__ c02)
{
    int i = blockIdx.x * blockDim.x + threadIdx.x;
    if (i >= NVOX * CO) return;
    int ch = i & 63;
    float r = out[i];
    float s = __bfloat162float(sc2[i]);
    out[i] = a2[ch] * r + c2[ch] + a02[ch] * s + c02[ch];
}

extern "C" void kernel_launch(void* const* d_in, const int* in_sizes, int n_in,
                              void* d_out, int out_size, void* d_ws, size_t ws_size,
                              hipStream_t stream)
{
    const float* feats = (const float*)d_in[0];
    const int*   nbr_a = (const int*)d_in[1];
    const int*   nbr_b = (const int*)d_in[2];
    const float* W1    = (const float*)d_in[3];
    const float* W1_2  = (const float*)d_in[4];
    const float* W2    = (const float*)d_in[5];
    const float* W3    = (const float*)d_in[6];
    const float* g0    = (const float*)d_in[7];
    const float* b0    = (const float*)d_in[8];
    const float* g0_2  = (const float*)d_in[9];
    const float* b0_2  = (const float*)d_in[10];
    const float* g1    = (const float*)d_in[11];
    const float* b1    = (const float*)d_in[12];
    const float* g2    = (const float*)d_in[13];
    const float* b2    = (const float*)d_in[14];

    char* ws = (char*)d_ws;
    size_t off = 0;
    auto alloc = [&](size_t bytes) { void* p = ws + off; off += (bytes + 255) & ~(size_t)255; return p; };
    __hip_bfloat16* sc1 = (__hip_bfloat16*)alloc((size_t)NVOX * CO * 2);
    __hip_bfloat16* r1  = (__hip_bfloat16*)alloc((size_t)NVOX * CO * 2);
    __hip_bfloat16* sc2 = (__hip_bfloat16*)alloc((size_t)NVOX * CO * 2);
    unsigned short* P1a = (unsigned short*)alloc((size_t)9 * 4 * 64 * 8 * 2);       // conv1 sc weights
    unsigned short* P1b = (unsigned short*)alloc((size_t)9 * 4 * 64 * 8 * 2);       // conv1 r weights
    unsigned short* P2a = (unsigned short*)alloc((size_t)9 * 2 * 4 * 64 * 8 * 2);   // conv2 sc folded
    unsigned short* P2b = (unsigned short*)alloc((size_t)9 * 2 * 4 * 64 * 8 * 2);   // conv2 r folded
    unsigned short* Bba = (unsigned short*)alloc((size_t)4 * 64 * 8 * 2);           // bias frags sc
    unsigned short* Bbb = (unsigned short*)alloc((size_t)4 * 64 * 8 * 2);           // bias frags r
    float* bias_sc = (float*)alloc(9 * 64 * 4);
    float* bias_r  = (float*)alloc(9 * 64 * 4);
    float* stats   = (float*)alloc(8 * 64 * 4);
    float* sum1a = stats,       *sq1a = stats + 64;
    float* sum1b = stats + 128, *sq1b = stats + 192;
    float* sum2a = stats + 256, *sq2a = stats + 320;
    float* sum2b = stats + 384, *sq2b = stats + 448;
    float* bn = (float*)alloc(8 * 64 * 4);
    float* a0 = bn,        *c0 = bn + 64;
    float* a1 = bn + 128,  *c1 = bn + 192;
    float* a02 = bn + 256, *c02 = bn + 320;
    float* a2 = bn + 384,  *c2 = bn + 448;

    hipMemsetAsync(stats, 0, 8 * 64 * 4, stream);

    const dim3 cgrid(1250, 2);   // 6250 waves per branch x 2 branches, exact
    const dim3 cblk(320);        // 5 waves per block

    prepack_w32<<<18, 64, 0, stream>>>(W1, W2, P1a, P1b);

    // pass 1: conv1 both branches in one dispatch (f32 input, lrelu, stats)
    conv_mfma2<32, true, true, false, true, true><<<cgrid, cblk, 0, stream>>>(
        feats, feats, nbr_a, nbr_b, P1a, P1b, nullptr, nullptr,
        sc1, r1, sum1a, sq1a, sum1b, sq1b);
    // BN1 finalize, fold into conv2 weights (packed), pack bias frags
    bn_fin<<<2, 64, 0, stream>>>(sum1a, sq1a, g0, b0, a0, c0, sum1b, sq1b, g1, b1, a1, c1);
    wtrans<<<18, 64, 0, stream>>>(W1_2, a0, c0, P2a, bias_sc, W3, a1, c1, P2b, bias_r);
    wpack_bias<<<2, 64, 0, stream>>>(bias_sc, Bba, bias_r, Bbb);
    // pass 2: conv2 both branches in one dispatch (bf16 input, bias, stats)
    conv_mfma2<64, false, false, true, true, false><<<cgrid, cblk, 0, stream>>>(
        sc1, r1, nbr_b, nbr_a, P2a, P2b, Bba, Bbb,
        sc2, d_out, sum2a, sq2a, sum2b, sq2b);
    // BN2 finalize + final fused add
    bn_fin<<<2, 64, 0, stream>>>(sum2a, sq2a, g0_2, b0_2, a02, c02, sum2b, sq2b, g2, b2, a2, c2);
    final_k<<<(NVOX * CO + 255) / 256, 256, 0, stream>>>((float*)d_out, sc2, a2, c2, a02, c02);
}